// Round 3
// baseline (188.947 us; speedup 1.0000x reference)
//
#include <hip/hip_runtime.h>

// out[p, :] = W[i1[p], :] + (i1[p] != i2[p] ? W[i2[p], :] : 0)
// P = B*S = 32768 positions, D = 512 fp32 = 128 float4 per row.
//
// v4: two-pass. The harness's per-iteration poison fills (2 x 411MB) thrash
// the 256MB Infinity Cache, so the gather's 36.6K random 2KB row reads go
// cold to HBM at poor random-granule efficiency (~3 TB/s effective).
// Pass 1 streams the whole 103MB table linearly (sequential HBM read at
// ~6.3 TB/s) to repopulate L3; pass 2's gathers then hit L3 instead of HBM.
// Output stores stay nontemporal so they don't evict the warmed table.

#define EMB_DIM 512
#define QUADS_PER_ROW (EMB_DIM / 4)   // 128
#define QPT 4                         // float4 per thread (gather)
#define TPP (QUADS_PER_ROW / QPT)     // 32 threads per position

typedef float f4 __attribute__((ext_vector_type(4)));

// ---- Pass 1: linear stream of the weight table to warm L3 ----
// 2048 blocks x 256 threads; each thread does up to WARM_ITERS strided
// dwordx4 loads (unrolled -> all independent, fully in flight).
#define WARM_BLOCKS 2048
#define WARM_ITERS  13   // ceil(6432896 quads / 524288 threads)

__global__ __launch_bounds__(256) void warm_kernel(
    const f4* __restrict__ w4, int total_quads)
{
    int base   = blockIdx.x * blockDim.x + threadIdx.x;
    int stride = WARM_BLOCKS * 256;
    float acc = 0.f;
#pragma unroll
    for (int k = 0; k < WARM_ITERS; ++k) {
        int i = base + k * stride;
        if (i < total_quads) {
            f4 v = w4[i];
            acc += v.x + v.y + v.z + v.w;   // keep loads alive
        }
    }
    asm volatile("" :: "v"(acc));           // no DCE (rule #17), no store
}

// ---- Pass 2: the gather (v3 structure, unchanged) ----
__global__ __launch_bounds__(256) void twohot_kernel(
    const int* __restrict__ idx1,
    const int* __restrict__ idx2,
    const f4*  __restrict__ w4,    // [VOCAB * 128]
    f4*        __restrict__ out4,  // [P * 128]
    int total_pos)
{
    int gid = blockIdx.x * blockDim.x + threadIdx.x;
    int pos = gid >> 5;              // gid / TPP
    int q   = gid & (TPP - 1);       // gid % TPP
    if (pos >= total_pos) return;

    int i1 = idx1[pos];
    int i2 = idx2[pos];

    const f4* r1 = w4 + (long)i1 * QUADS_PER_ROW + q;
    f4 v0 = r1[0 * TPP];
    f4 v1 = r1[1 * TPP];
    f4 v2 = r1[2 * TPP];
    f4 v3 = r1[3 * TPP];

    if (i2 != i1) {
        const f4* r2 = w4 + (long)i2 * QUADS_PER_ROW + q;
        f4 u0 = r2[0 * TPP];
        f4 u1 = r2[1 * TPP];
        f4 u2 = r2[2 * TPP];
        f4 u3 = r2[3 * TPP];
        v0 += u0; v1 += u1; v2 += u2; v3 += u3;
    }

    f4* o = out4 + (long)pos * QUADS_PER_ROW + q;
    __builtin_nontemporal_store(v0, o + 0 * TPP);
    __builtin_nontemporal_store(v1, o + 1 * TPP);
    __builtin_nontemporal_store(v2, o + 2 * TPP);
    __builtin_nontemporal_store(v3, o + 3 * TPP);
}

extern "C" void kernel_launch(void* const* d_in, const int* in_sizes, int n_in,
                              void* d_out, int out_size, void* d_ws, size_t ws_size,
                              hipStream_t stream) {
    const int* idx1 = (const int*)d_in[0];   // input_one [B,S] int32
    const int* idx2 = (const int*)d_in[1];   // input_two [B,S] int32
    const f4*  w4   = (const f4*)d_in[2];    // weight [VOCAB, 512] fp32
    f4* out4        = (f4*)d_out;            // [B,S,512] fp32

    int total_pos   = out_size / EMB_DIM;    // out_size = B*S*512 f32 elements
    // weight quads: in_sizes[2] is the weight's element count (VOCAB*512)
    int weight_quads = in_sizes[2] / 4;

    warm_kernel<<<WARM_BLOCKS, 256, 0, stream>>>(w4, weight_quads);

    int total_threads = total_pos * TPP;
    int block = 256;
    int grid  = (total_threads + block - 1) / block;
    twohot_kernel<<<grid, block, 0, stream>>>(idx1, idx2, w4, out4, total_pos);
}

// Round 4
// 171.018 us; speedup vs baseline: 1.1048x; 1.1048x over previous
//
#include <hip/hip_runtime.h>

// out[p, :] = W[i1[p], :] + (i1[p] != i2[p] ? W[i2[p], :] : 0)
// P = B*S = 32768 positions, D = 512 fp32 = 128 float4 per row.
//
// v5: v3 structure, but weight gathers use NONTEMPORAL loads (nt flag,
// L1-bypass). Evidence: warm-L3 pass was a clean null (+16.7us = its own
// cost) and per-thread MLP 2->8 was a null => gather is capped by the
// per-CU outstanding-miss path on scattered reads, not by data source or
// issue shape. nt loads stream past the vector L1 into the deeper L2/
// fabric queues. No intra-kernel L1 reuse exists (random rows), so the
// bypass is free. Output stores stay nontemporal.

#define EMB_DIM 512
#define QUADS_PER_ROW (EMB_DIM / 4)   // 128
#define QPT 4                         // float4 per thread
#define TPP (QUADS_PER_ROW / QPT)     // 32 threads per position

typedef float f4 __attribute__((ext_vector_type(4)));

__global__ __launch_bounds__(256) void twohot_kernel(
    const int* __restrict__ idx1,
    const int* __restrict__ idx2,
    const f4*  __restrict__ w4,    // [VOCAB * 128]
    f4*        __restrict__ out4,  // [P * 128]
    int total_pos)
{
    int gid = blockIdx.x * blockDim.x + threadIdx.x;
    int pos = gid >> 5;              // gid / TPP
    int q   = gid & (TPP - 1);       // gid % TPP
    if (pos >= total_pos) return;

    int i1 = idx1[pos];
    int i2 = idx2[pos];

    // Row 1: 4 independent 16B nontemporal gathers (L1-bypass).
    const f4* r1 = w4 + (long)i1 * QUADS_PER_ROW + q;
    f4 v0 = __builtin_nontemporal_load(r1 + 0 * TPP);
    f4 v1 = __builtin_nontemporal_load(r1 + 1 * TPP);
    f4 v2 = __builtin_nontemporal_load(r1 + 2 * TPP);
    f4 v3 = __builtin_nontemporal_load(r1 + 3 * TPP);

    // Row 2 only when distinct (P(equal) ~ 1/50257 -> no real divergence).
    if (i2 != i1) {
        const f4* r2 = w4 + (long)i2 * QUADS_PER_ROW + q;
        f4 u0 = __builtin_nontemporal_load(r2 + 0 * TPP);
        f4 u1 = __builtin_nontemporal_load(r2 + 1 * TPP);
        f4 u2 = __builtin_nontemporal_load(r2 + 2 * TPP);
        f4 u3 = __builtin_nontemporal_load(r2 + 3 * TPP);
        v0 += u0; v1 += u1; v2 += u2; v3 += u3;
    }

    // Write-once output: nontemporal stores.
    f4* o = out4 + (long)pos * QUADS_PER_ROW + q;
    __builtin_nontemporal_store(v0, o + 0 * TPP);
    __builtin_nontemporal_store(v1, o + 1 * TPP);
    __builtin_nontemporal_store(v2, o + 2 * TPP);
    __builtin_nontemporal_store(v3, o + 3 * TPP);
}

extern "C" void kernel_launch(void* const* d_in, const int* in_sizes, int n_in,
                              void* d_out, int out_size, void* d_ws, size_t ws_size,
                              hipStream_t stream) {
    const int* idx1 = (const int*)d_in[0];   // input_one [B,S] int32
    const int* idx2 = (const int*)d_in[1];   // input_two [B,S] int32
    const f4*  w4   = (const f4*)d_in[2];    // weight [VOCAB, 512] fp32
    f4* out4        = (f4*)d_out;            // [B,S,512] fp32

    int total_pos     = out_size / EMB_DIM;  // out_size = B*S*512 f32 elements
    int total_threads = total_pos * TPP;
    int block = 256;
    int grid  = (total_threads + block - 1) / block;
    twohot_kernel<<<grid, block, 0, stream>>>(idx1, idx2, w4, out4, total_pos);
}